// Round 8
// baseline (87.224 us; speedup 1.0000x reference)
//
#include <hip/hip_runtime.h>
#include <hip/hip_bf16.h>
#include <math.h>

#define NTOK 4096
#define DEMB 256
#define NHEAD 4
#define HD 64

typedef short bf16x8 __attribute__((ext_vector_type(8)));
typedef short bf16x4 __attribute__((ext_vector_type(4)));
typedef float f32x4 __attribute__((ext_vector_type(4)));

__device__ __forceinline__ unsigned short f2b(float f) {
  union { float f; unsigned u; } v; v.f = f;
  return (unsigned short)((v.u + 0x7FFFu + ((v.u >> 16) & 1u)) >> 16);
}
__device__ __forceinline__ unsigned pack2(float lo, float hi) {
  return (unsigned)f2b(lo) | ((unsigned)f2b(hi) << 16);
}

// ---- prep 1: transpose+cast the 4 weight matrices to bf16 [out][in] ----
__global__ void wtrans_kernel(const float* wq, const float* wk, const float* wv,
                              const float* wo, unsigned short* wt) {
  int idx = blockIdx.x * 256 + threadIdx.x;  // 4 * 256 * 256
  int m = idx >> 16, rest = idx & 0xFFFF;
  int o = rest >> 8, i = rest & 255;
  const float* w = (m == 0) ? wq : (m == 1) ? wk : (m == 2) ? wv : wo;
  wt[idx] = f2b(w[i * 256 + o]);
}

// ---- prep 2: RoPE cos/sin table [NTOK][32] as float2(cos,sin) ----
__global__ void cs_kernel(float2* cs) {
  int idx = blockIdx.x * 256 + threadIdx.x;  // 4096*32
  int n = idx >> 5, p = idx & 31;
  int j = p & 15;
  float f = powf(10000.0f, -(float)j / 16.0f);
  float ang = ((p < 16) ? (float)(n & 63) : (float)(n >> 6)) * f;
  cs[idx] = make_float2(cosf(ang), sinf(ang));
}

// ---- fused QKV projection + bias + RoPE; z = 0:q 1:k 2:v ----
// outputs: qp/kp bf16 [h][n][d] (q pre-scaled by 0.125*log2e).
// vt bf16 [h][d][n'] where the token dim is permuted within each 32-token
// block so PV's A-fragment is the attn wave's own P registers:
//   k-position kappa  <->  token 16*((kappa>>2)&1) + 4*(kappa>>3) + (kappa&3)
__global__ __launch_bounds__(256) void qkvproj_kernel(
    const float* q, const float* k, const float* v, const unsigned short* wt,
    const float* bq, const float* bk, const float* bv, const float2* cs,
    unsigned short* qp, unsigned short* kp, unsigned short* vt) {
  int which = blockIdx.z;
  int wave = threadIdx.x >> 6, lane = threadIdx.x & 63;
  int col = lane & 15, g = lane >> 4;
  int mbase = blockIdx.x * 64 + wave * 16;
  int nbase = blockIdx.y * 64;
  const float* X = (which == 0) ? q : (which == 1) ? k : v;
  const unsigned short* W = wt + which * 65536;
  const float* bias = (which == 0) ? bq : (which == 1) ? bk : bv;

  f32x4 acc[4] = {};
  const float* ap0 = X + (mbase + col) * 256 + g * 8;
#pragma unroll
  for (int ks = 0; ks < 256; ks += 32) {
    float4 a0 = *(const float4*)(ap0 + ks);
    float4 a1 = *(const float4*)(ap0 + ks + 4);
    bf16x8 af;
    af[0] = (short)f2b(a0.x); af[1] = (short)f2b(a0.y);
    af[2] = (short)f2b(a0.z); af[3] = (short)f2b(a0.w);
    af[4] = (short)f2b(a1.x); af[5] = (short)f2b(a1.y);
    af[6] = (short)f2b(a1.z); af[7] = (short)f2b(a1.w);
#pragma unroll
    for (int nt = 0; nt < 4; ++nt) {
      bf16x8 bf_ = *(const bf16x8*)(W + (nbase + nt * 16 + col) * 256 + ks + g * 8);
      acc[nt] = __builtin_amdgcn_mfma_f32_16x16x32_bf16(af, bf_, acc[nt], 0, 0, 0);
    }
  }

  if (which == 2) {
    // tokens handled by this lane: t = mbase + g*4 + r (r=0..3, consecutive)
    // permuted position: block (t>>5)*32 + 8*g + 4*((mbase>>4)&1) + r
    int kpos = ((mbase >> 5) << 5) + 8 * g + 4 * ((mbase >> 4) & 1);
#pragma unroll
    for (int nt = 0; nt < 4; ++nt) {
      int c = nbase + nt * 16 + col;
      float b = bias[c];
      bf16x4 pk;
#pragma unroll
      for (int r = 0; r < 4; ++r) pk[r] = (short)f2b(acc[nt][r] + b);
      *(bf16x4*)(vt + c * NTOK + kpos) = pk;
    }
  } else {
    const float QSC = 0.18033688f;  // 0.125 * log2(e): fold softmax scale + exp2 base
    unsigned short* dst = (which == 0) ? qp : kp;
#pragma unroll
    for (int nt = 0; nt < 4; ++nt) {
      int c = nbase + nt * 16 + col;
      float b = bias[c];
#pragma unroll
      for (int r = 0; r < 4; ++r) {
        int t = mbase + g * 4 + r;
        float val = acc[nt][r] + b;
        float2 csv = cs[t * 32 + ((c & 63) >> 1)];
        float pv = __shfl_xor(val, 1);
        float sn = (c & 1) ? csv.y : -csv.y;
        val = val * csv.x + pv * sn;
        if (which == 0) val *= QSC;
        dst[((c >> 6) * NTOK + t) * HD + (c & 63)] = f2b(val);
      }
    }
  }
}

// ---- flash attention, QR=256 per block, grid-level kv-split 4 ----
// block = 512 thr = 8 waves; wave w owns q-rows [qb + w*32, +32); ALL waves
// share one 64-key K/V tile stream (LDS 2 x 16KB double-buffer, XOR-swizzled)
// covering kv slice [ks*1024, +1024). Per-block partial (O, m, l) -> ws;
// merge_kernel combines the 4 kv-partials. grid = 16 qtiles x 4 heads x 4 ks
// = 256 blocks; XCD (id&7, m09) -> head = xcd>>1 for per-XCD L2 residency.
// KV global traffic: 256 blocks x 256KB = 72MB total (R7: 256MB).
__global__ __launch_bounds__(512, 2) void attn_kernel(
    const unsigned short* qp, const unsigned short* kp,
    const unsigned short* vt, float* pO, float* pml) {
  __shared__ alignas(16) unsigned char lds[32768];
  int id = blockIdx.x;
  int xcd = id & 7;
  int head = xcd >> 1;
  int kshi = xcd & 1;
  int rest = id >> 3;          // 0..31
  int qtile = rest >> 1;       // 0..15
  int ks = kshi * 2 + (rest & 1);
  int qb = qtile * 256;
  int slot = (head * 16 + qtile) * 4 + ks;
  int w = threadIdx.x >> 6, lane = threadIdx.x & 63;
  int col = lane & 15, g = lane >> 4;
  int sid = threadIdx.x;       // staging id: 512 chunks of 16B for K and V
  int stok = sid >> 3, spart = sid & 7;
  unsigned soff = (unsigned)(stok * 128) +
                  (unsigned)((spart * 16) ^ ((stok & 7) << 4));

  const unsigned short* kgp = kp + (head * NTOK + ks * 1024) * HD;
  const unsigned short* vgp = vt + head * HD * NTOK + ks * 1024;

  bf16x8 skr, svr;
  auto stage_issue = [&](int t) {
    skr = *(const bf16x8*)(kgp + (t * 64 + stok) * HD + spart * 8);
    svr = *(const bf16x8*)(vgp + stok * NTOK + t * 64 + spart * 8);
  };
  auto stage_write = [&](int buf) {
    *(bf16x8*)(lds + (unsigned)buf * 16384u + soff) = skr;
    *(bf16x8*)(lds + (unsigned)buf * 16384u + 8192u + soff) = svr;
  };

  // Q fragments: 32 q-rows per wave -> qf[qt][half]
  bf16x8 qf[2][2];
  {
    const unsigned short* qr = qp + (head * NTOK + qb + w * 32) * HD;
#pragma unroll
    for (int qt = 0; qt < 2; ++qt)
#pragma unroll
      for (int h2 = 0; h2 < 2; ++h2)
        qf[qt][h2] = *(const bf16x8*)(qr + (qt * 16 + col) * HD + h2 * 32 + g * 8);
  }

  stage_issue(0);
  stage_write(0);       // compiler inserts vmcnt wait
  stage_issue(1);
  __syncthreads();

  f32x4 acco[4][2] = {};
  float mrow[2] = {-1e30f, -1e30f}, lrow[2] = {0.f, 0.f};

  for (int t = 0; t < 16; ++t) {
    int cur = t & 1;
    if (t < 15) {
      stage_write(cur ^ 1);            // buf read last iter; barrier passed
      if (t < 14) stage_issue(t + 2);  // overlap loads with compute below
    }
    unsigned kb = (unsigned)cur * 16384u, vb = (unsigned)cur * 16384u + 8192u;

    // S^T = K * Q^T : D col=q, rows=kv
    f32x4 st[4][2] = {};
#pragma unroll
    for (int mt = 0; mt < 4; ++mt) {
      int tok = mt * 16 + col;
      unsigned ro = kb + (unsigned)(tok * 128) + (unsigned)((g * 16) ^ ((tok & 7) << 4));
      bf16x8 kf0 = *(const bf16x8*)(lds + ro);
      bf16x8 kf1 = *(const bf16x8*)(lds + (ro ^ 64u));
#pragma unroll
      for (int qt = 0; qt < 2; ++qt) {
        st[mt][qt] = __builtin_amdgcn_mfma_f32_16x16x32_bf16(kf0, qf[qt][0], st[mt][qt], 0, 0, 0);
        st[mt][qt] = __builtin_amdgcn_mfma_f32_16x16x32_bf16(kf1, qf[qt][1], st[mt][qt], 0, 0, 0);
      }
    }

    // online softmax per q-subtile (log2 domain; scale folded into Q)
    float fac[2];
    unsigned pw[2][2][4];
#pragma unroll
    for (int qt = 0; qt < 2; ++qt) {
      float pm = mrow[qt];
#pragma unroll
      for (int mt = 0; mt < 4; ++mt)
#pragma unroll
        for (int r = 0; r < 4; ++r) pm = fmaxf(pm, st[mt][qt][r]);
      pm = fmaxf(pm, __shfl_xor(pm, 16));
      pm = fmaxf(pm, __shfl_xor(pm, 32));
      fac[qt] = exp2f(mrow[qt] - pm);
      mrow[qt] = pm;
      float ps = 0.f;
      float p[4][4];
#pragma unroll
      for (int mt = 0; mt < 4; ++mt)
#pragma unroll
        for (int r = 0; r < 4; ++r) {
          p[mt][r] = exp2f(st[mt][qt][r] - pm);
          ps += p[mt][r];
        }
      ps += __shfl_xor(ps, 16);
      ps += __shfl_xor(ps, 32);
      lrow[qt] = lrow[qt] * fac[qt] + ps;
      // pack P -> bf16 pairs (RNE via f2b bit-trick; cvt_pk truncates -> R6 fail)
#pragma unroll
      for (int kk = 0; kk < 2; ++kk) {
        pw[qt][kk][0] = pack2(p[2 * kk][0], p[2 * kk][1]);
        pw[qt][kk][1] = pack2(p[2 * kk][2], p[2 * kk][3]);
        pw[qt][kk][2] = pack2(p[2 * kk + 1][0], p[2 * kk + 1][1]);
        pw[qt][kk][3] = pack2(p[2 * kk + 1][2], p[2 * kk + 1][3]);
      }
    }

    // rescale O accumulators (O rows are q = g*4+r; fac lives at lane q)
    float frow[2][4];
#pragma unroll
    for (int qt = 0; qt < 2; ++qt)
#pragma unroll
      for (int r = 0; r < 4; ++r) frow[qt][r] = __shfl(fac[qt], g * 4 + r);
#pragma unroll
    for (int nt = 0; nt < 4; ++nt)
#pragma unroll
      for (int qt = 0; qt < 2; ++qt) {
        acco[nt][qt][0] *= frow[qt][0]; acco[nt][qt][1] *= frow[qt][1];
        acco[nt][qt][2] *= frow[qt][2]; acco[nt][qt][3] *= frow[qt][3];
      }

    // O += P * V (V token-permuted so A-fragment = own packed P)
#pragma unroll
    for (int kk = 0; kk < 2; ++kk) {
#pragma unroll
      for (int nt = 0; nt < 4; ++nt) {
        int d = nt * 16 + col;
        unsigned off = vb + (unsigned)(d * 128) +
                       (unsigned)((kk * 64 + g * 16) ^ ((d & 7) << 4));
        bf16x8 vf = *(const bf16x8*)(lds + off);
#pragma unroll
        for (int qt = 0; qt < 2; ++qt) {
          union { unsigned u[4]; bf16x8 v; } pf;
          pf.u[0] = pw[qt][kk][0]; pf.u[1] = pw[qt][kk][1];
          pf.u[2] = pw[qt][kk][2]; pf.u[3] = pw[qt][kk][3];
          acco[nt][qt] = __builtin_amdgcn_mfma_f32_16x16x32_bf16(pf.v, vf, acco[nt][qt], 0, 0, 0);
        }
      }
    }
    __syncthreads();
  }

  // ---- write this block's kv-partial (O unnormalized, m, l) to ws ----
#pragma unroll
  for (int nt = 0; nt < 4; ++nt)
#pragma unroll
    for (int qt = 0; qt < 2; ++qt)
#pragma unroll
      for (int r = 0; r < 4; ++r)
        pO[slot * 16384 + (w * 32 + qt * 16 + g * 4 + r) * 64 + nt * 16 + col] =
            acco[nt][qt][r];
  if (g == 0) {
#pragma unroll
    for (int qt = 0; qt < 2; ++qt) {
      pml[slot * 512 + (w * 32 + qt * 16 + col) * 2 + 0] = mrow[qt];
      pml[slot * 512 + (w * 32 + qt * 16 + col) * 2 + 1] = lrow[qt];
    }
  }
}

// ---- merge the 4 kv-partials per (head, qtile) -> att bf16 [n][256] ----
__global__ __launch_bounds__(256) void merge_kernel(
    const float* pO, const float* pml, unsigned short* att) {
  int bid = blockIdx.x;            // 256 = 64 groups x 4 row-quarters
  int group = bid >> 2, quarter = bid & 3;
  int head = group >> 4, qtile = group & 15;
  int t = threadIdx.x;
  int qloc = quarter * 64 + (t >> 2);
  int d0 = (t & 3) * 16;
  const float* mlb = pml + (group * 4) * 512 + qloc * 2;
  float mx = -1e30f;
#pragma unroll
  for (int ks = 0; ks < 4; ++ks) mx = fmaxf(mx, mlb[ks * 512]);
  float den = 0.f, num[16] = {};
#pragma unroll
  for (int ks = 0; ks < 4; ++ks) {
    float wgt = exp2f(mlb[ks * 512] - mx);
    den += wgt * mlb[ks * 512 + 1];
    const float* ob = pO + ((group * 4 + ks) * 256 + qloc) * 64 + d0;
#pragma unroll
    for (int i = 0; i < 16; ++i) num[i] += wgt * ob[i];
  }
  float inv = 1.0f / den;
  union { unsigned short s[16]; bf16x8 v[2]; } ov;
#pragma unroll
  for (int i = 0; i < 16; ++i) ov.s[i] = f2b(num[i] * inv);
  unsigned short* dst = att + (qtile * 256 + qloc) * DEMB + head * HD + d0;
  *(bf16x8*)dst = ov.v[0];
  *(bf16x8*)(dst + 8) = ov.v[1];
}

// ---- output projection: att bf16 [n][256] @ wo + bo -> f32 out ----
__global__ __launch_bounds__(256) void outproj_kernel(
    const unsigned short* att, const unsigned short* wt_o, const float* bo,
    float* out) {
  int wave = threadIdx.x >> 6, lane = threadIdx.x & 63;
  int col = lane & 15, g = lane >> 4;
  int mbase = blockIdx.x * 64 + wave * 16;
  int nbase = blockIdx.y * 64;
  f32x4 acc[4] = {};
#pragma unroll
  for (int ks = 0; ks < 256; ks += 32) {
    bf16x8 af = *(const bf16x8*)(att + (mbase + col) * 256 + ks + g * 8);
#pragma unroll
    for (int nt = 0; nt < 4; ++nt) {
      bf16x8 bf_ = *(const bf16x8*)(wt_o + (nbase + nt * 16 + col) * 256 + ks + g * 8);
      acc[nt] = __builtin_amdgcn_mfma_f32_16x16x32_bf16(af, bf_, acc[nt], 0, 0, 0);
    }
  }
#pragma unroll
  for (int nt = 0; nt < 4; ++nt) {
    int c = nbase + nt * 16 + col;
    float b = bo[c];
#pragma unroll
    for (int r = 0; r < 4; ++r)
      out[(mbase + g * 4 + r) * 256 + c] = acc[nt][r] + b;
  }
}

extern "C" void kernel_launch(void* const* d_in, const int* in_sizes, int n_in,
                              void* d_out, int out_size, void* d_ws, size_t ws_size,
                              hipStream_t stream) {
  const float* q  = (const float*)d_in[0];
  const float* k  = (const float*)d_in[1];
  const float* v  = (const float*)d_in[2];
  const float* wq = (const float*)d_in[3];
  const float* bq = (const float*)d_in[4];
  const float* wk = (const float*)d_in[5];
  const float* bk = (const float*)d_in[6];
  const float* wv = (const float*)d_in[7];
  const float* bv = (const float*)d_in[8];
  const float* wo = (const float*)d_in[9];
  const float* bo = (const float*)d_in[10];
  float* out = (float*)d_out;

  char* ws = (char*)d_ws;
  float2* cs         = (float2*)ws;                          // [0, 1MB)
  unsigned short* wt = (unsigned short*)(ws + (1u << 20));   // [1, 1.5MB)
  unsigned short* qp = (unsigned short*)(ws + 1536u * 1024u); // [1.5, 3.5MB)
  unsigned short* kp = qp + NHEAD * NTOK * HD;               // [3.5, 5.5MB)
  unsigned short* vt = kp + NHEAD * NTOK * HD;               // [5.5, 7.5MB)
  unsigned short* att = vt + NHEAD * NTOK * HD;              // [7.5, 9.5MB)
  float* pO  = (float*)(ws + 9728u * 1024u);                 // [9.5, 25.5MB)
  float* pml = (float*)(ws + 26112u * 1024u);                // [25.5, 26MB)

  wtrans_kernel<<<1024, 256, 0, stream>>>(wq, wk, wv, wo, wt);
  cs_kernel<<<512, 256, 0, stream>>>(cs);
  qkvproj_kernel<<<dim3(64, 4, 3), 256, 0, stream>>>(q, k, v, wt, bq, bk, bv, cs,
                                                     qp, kp, vt);
  attn_kernel<<<256, 512, 0, stream>>>(qp, kp, vt, pO, pml);
  merge_kernel<<<256, 256, 0, stream>>>(pO, pml, att);
  outproj_kernel<<<dim3(64, 4), 256, 0, stream>>>(att, wt + 3 * 65536, bo, out);
}

// Round 9
// 78.071 us; speedup vs baseline: 1.1172x; 1.1172x over previous
//
#include <hip/hip_runtime.h>
#include <hip/hip_bf16.h>
#include <math.h>

#define NTOK 4096
#define DEMB 256
#define NHEAD 4
#define HD 64

typedef short bf16x8 __attribute__((ext_vector_type(8)));
typedef short bf16x4 __attribute__((ext_vector_type(4)));
typedef float f32x4 __attribute__((ext_vector_type(4)));

__device__ __forceinline__ unsigned short f2b(float f) {
  union { float f; unsigned u; } v; v.f = f;
  return (unsigned short)((v.u + 0x7FFFu + ((v.u >> 16) & 1u)) >> 16);
}
// RTN (ties-away) pair pack: 5 literal-friendly VOP2s, vs ~8 for RNE f2b pair.
// Differs from RNE only on exact-tie mantissas (measure-zero for exp2 outputs).
__device__ __forceinline__ unsigned packrtn(float lo, float hi) {
  union { float f; unsigned u; } a, b; a.f = lo; b.f = hi;
  return ((a.u + 0x8000u) >> 16) | ((b.u + 0x8000u) & 0xFFFF0000u);
}

// ---- prep 1: transpose+cast the 4 weight matrices to bf16 [out][in] ----
__global__ void wtrans_kernel(const float* wq, const float* wk, const float* wv,
                              const float* wo, unsigned short* wt) {
  int idx = blockIdx.x * 256 + threadIdx.x;  // 4 * 256 * 256
  int m = idx >> 16, rest = idx & 0xFFFF;
  int o = rest >> 8, i = rest & 255;
  const float* w = (m == 0) ? wq : (m == 1) ? wk : (m == 2) ? wv : wo;
  wt[idx] = f2b(w[i * 256 + o]);
}

// ---- prep 2: RoPE cos/sin table [NTOK][32] as float2(cos,sin) ----
__global__ void cs_kernel(float2* cs) {
  int idx = blockIdx.x * 256 + threadIdx.x;  // 4096*32
  int n = idx >> 5, p = idx & 31;
  int j = p & 15;
  float f = powf(10000.0f, -(float)j / 16.0f);
  float ang = ((p < 16) ? (float)(n & 63) : (float)(n >> 6)) * f;
  cs[idx] = make_float2(cosf(ang), sinf(ang));
}

// ---- fused QKV projection + bias + RoPE; z = 0:q 1:k 2:v ----
// outputs: qp/kp bf16 [h][n][d] (q pre-scaled by 0.125*log2e).
// vt bf16 [h][d][n'] with token dim permuted within each 32-token block so
// PV's A-fragment is the attn wave's own P registers.
__global__ __launch_bounds__(256) void qkvproj_kernel(
    const float* q, const float* k, const float* v, const unsigned short* wt,
    const float* bq, const float* bk, const float* bv, const float2* cs,
    unsigned short* qp, unsigned short* kp, unsigned short* vt) {
  int which = blockIdx.z;
  int wave = threadIdx.x >> 6, lane = threadIdx.x & 63;
  int col = lane & 15, g = lane >> 4;
  int mbase = blockIdx.x * 64 + wave * 16;
  int nbase = blockIdx.y * 64;
  const float* X = (which == 0) ? q : (which == 1) ? k : v;
  const unsigned short* W = wt + which * 65536;
  const float* bias = (which == 0) ? bq : (which == 1) ? bk : bv;

  f32x4 acc[4] = {};
  const float* ap0 = X + (mbase + col) * 256 + g * 8;
#pragma unroll
  for (int ks = 0; ks < 256; ks += 32) {
    float4 a0 = *(const float4*)(ap0 + ks);
    float4 a1 = *(const float4*)(ap0 + ks + 4);
    bf16x8 af;
    af[0] = (short)f2b(a0.x); af[1] = (short)f2b(a0.y);
    af[2] = (short)f2b(a0.z); af[3] = (short)f2b(a0.w);
    af[4] = (short)f2b(a1.x); af[5] = (short)f2b(a1.y);
    af[6] = (short)f2b(a1.z); af[7] = (short)f2b(a1.w);
#pragma unroll
    for (int nt = 0; nt < 4; ++nt) {
      bf16x8 bf_ = *(const bf16x8*)(W + (nbase + nt * 16 + col) * 256 + ks + g * 8);
      acc[nt] = __builtin_amdgcn_mfma_f32_16x16x32_bf16(af, bf_, acc[nt], 0, 0, 0);
    }
  }

  if (which == 2) {
    int kpos = ((mbase >> 5) << 5) + 8 * g + 4 * ((mbase >> 4) & 1);
#pragma unroll
    for (int nt = 0; nt < 4; ++nt) {
      int c = nbase + nt * 16 + col;
      float b = bias[c];
      bf16x4 pk;
#pragma unroll
      for (int r = 0; r < 4; ++r) pk[r] = (short)f2b(acc[nt][r] + b);
      *(bf16x4*)(vt + c * NTOK + kpos) = pk;
    }
  } else {
    const float QSC = 0.18033688f;  // 0.125 * log2(e)
    unsigned short* dst = (which == 0) ? qp : kp;
#pragma unroll
    for (int nt = 0; nt < 4; ++nt) {
      int c = nbase + nt * 16 + col;
      float b = bias[c];
#pragma unroll
      for (int r = 0; r < 4; ++r) {
        int t = mbase + g * 4 + r;
        float val = acc[nt][r] + b;
        float2 csv = cs[t * 32 + ((c & 63) >> 1)];
        float pv = __shfl_xor(val, 1);
        float sn = (c & 1) ? csv.y : -csv.y;
        val = val * csv.x + pv * sn;
        if (which == 0) val *= QSC;
        dst[((c >> 6) * NTOK + t) * HD + (c & 63)] = f2b(val);
      }
    }
  }
}

// ---- flash attention: wave = 16 q-rows, block = 8 waves = 128 rows ----
// grid = 4 heads x 32 qtiles x 4 kv-slices = 512 blocks = 2 blocks/CU
// (4 waves/SIMD; R8 showed 1 block/CU + serial softmax chain = latency-bound).
// T13 defer-max: skip cross-lane max reduce + O-rescale while all lanes'
// tile-max <= mrow+8 (P bounded by 2^8; merge algebra is max-agnostic).
// l kept as per-lane partial (replicas own disjoint kv), reduced post-loop.
__global__ __launch_bounds__(512, 4) void attn_kernel(
    const unsigned short* qp, const unsigned short* kp,
    const unsigned short* vt, float* pO, float* pml) {
  __shared__ alignas(16) unsigned char lds[32768];
  int id = blockIdx.x;
  int xcd = id & 7;
  int head = xcd >> 1;               // XCD-local head (id%8 -> XCD, m09)
  int rest = id >> 3;                // 0..63
  int qtile = rest >> 1;             // 0..31
  int ks = (xcd & 1) * 2 + (rest & 1);
  int qb = qtile * 128;
  int slot = (head * 32 + qtile) * 4 + ks;
  int w = threadIdx.x >> 6, lane = threadIdx.x & 63;
  int col = lane & 15, g = lane >> 4;
  int stok = threadIdx.x >> 3, spart = threadIdx.x & 7;  // staging: 512 x 16B
  unsigned soff = (unsigned)(stok * 128) +
                  (unsigned)((spart * 16) ^ ((stok & 7) << 4));

  const unsigned short* kgp = kp + (head * NTOK + ks * 1024) * HD;
  const unsigned short* vgp = vt + head * HD * NTOK + ks * 1024;

  bf16x8 skr, svr;
  auto stage_issue = [&](int t) {
    skr = *(const bf16x8*)(kgp + (t * 64 + stok) * HD + spart * 8);
    svr = *(const bf16x8*)(vgp + stok * NTOK + t * 64 + spart * 8);
  };
  auto stage_write = [&](int buf) {
    *(bf16x8*)(lds + (unsigned)buf * 16384u + soff) = skr;
    *(bf16x8*)(lds + (unsigned)buf * 16384u + 8192u + soff) = svr;
  };

  // Q fragments for this wave's 16 q-rows
  bf16x8 qf[2];
  {
    const unsigned short* qr = qp + (head * NTOK + qb + w * 16) * HD;
#pragma unroll
    for (int h2 = 0; h2 < 2; ++h2)
      qf[h2] = *(const bf16x8*)(qr + col * HD + h2 * 32 + g * 8);
  }

  stage_issue(0);
  stage_write(0);       // compiler inserts vmcnt wait
  stage_issue(1);
  __syncthreads();

  f32x4 acco[4] = {};
  float mrow = -1e30f, lrow = 0.f;

  for (int t = 0; t < 16; ++t) {
    int cur = t & 1;
    if (t < 15) {
      stage_write(cur ^ 1);            // buf read last iter; barrier passed
      if (t < 14) stage_issue(t + 2);  // overlap loads with compute below
    }
    unsigned kb = (unsigned)cur * 16384u, vb = (unsigned)cur * 16384u + 8192u;

    // S^T = K * Q^T : D col=q, rows=kv
    f32x4 st[4] = {};
#pragma unroll
    for (int mt = 0; mt < 4; ++mt) {
      int tok = mt * 16 + col;
      unsigned ro = kb + (unsigned)(tok * 128) + (unsigned)((g * 16) ^ ((tok & 7) << 4));
      bf16x8 kf0 = *(const bf16x8*)(lds + ro);
      bf16x8 kf1 = *(const bf16x8*)(lds + (ro ^ 64u));
      st[mt] = __builtin_amdgcn_mfma_f32_16x16x32_bf16(kf0, qf[0], st[mt], 0, 0, 0);
      st[mt] = __builtin_amdgcn_mfma_f32_16x16x32_bf16(kf1, qf[1], st[mt], 0, 0, 0);
    }

    // tile max (per-lane only; cross-lane reduce deferred via T13)
    float pm = fmaxf(fmaxf(st[0][0], st[0][1]), fmaxf(st[0][2], st[0][3]));
#pragma unroll
    for (int mt = 1; mt < 4; ++mt)
      pm = fmaxf(pm, fmaxf(fmaxf(st[mt][0], st[mt][1]), fmaxf(st[mt][2], st[mt][3])));
    if (!__all(pm <= mrow + 8.0f)) {
      float nm = fmaxf(pm, __shfl_xor(pm, 16));
      nm = fmaxf(nm, __shfl_xor(nm, 32));
      nm = fmaxf(nm, mrow);
      float fac = exp2f(mrow - nm);
      mrow = nm;
      lrow *= fac;
      float fr0 = __shfl(fac, g * 4 + 0), fr1 = __shfl(fac, g * 4 + 1);
      float fr2 = __shfl(fac, g * 4 + 2), fr3 = __shfl(fac, g * 4 + 3);
#pragma unroll
      for (int nt = 0; nt < 4; ++nt) {
        acco[nt][0] *= fr0; acco[nt][1] *= fr1;
        acco[nt][2] *= fr2; acco[nt][3] *= fr3;
      }
    }

    // P = exp2(S - m), per-lane l accumulation, RTN pair pack
    float p[4][4];
#pragma unroll
    for (int mt = 0; mt < 4; ++mt)
#pragma unroll
      for (int r = 0; r < 4; ++r) {
        p[mt][r] = exp2f(st[mt][r] - mrow);
        lrow += p[mt][r];
      }
    unsigned pw[2][4];
#pragma unroll
    for (int kk = 0; kk < 2; ++kk) {
      pw[kk][0] = packrtn(p[2 * kk][0], p[2 * kk][1]);
      pw[kk][1] = packrtn(p[2 * kk][2], p[2 * kk][3]);
      pw[kk][2] = packrtn(p[2 * kk + 1][0], p[2 * kk + 1][1]);
      pw[kk][3] = packrtn(p[2 * kk + 1][2], p[2 * kk + 1][3]);
    }

    // O += P * V (V token-permuted so A-fragment = own packed P)
#pragma unroll
    for (int kk = 0; kk < 2; ++kk) {
      union { unsigned u[4]; bf16x8 v; } pf;
      pf.u[0] = pw[kk][0]; pf.u[1] = pw[kk][1];
      pf.u[2] = pw[kk][2]; pf.u[3] = pw[kk][3];
#pragma unroll
      for (int nt = 0; nt < 4; ++nt) {
        int d = nt * 16 + col;
        unsigned off = vb + (unsigned)(d * 128) +
                       (unsigned)((kk * 64 + g * 16) ^ ((d & 7) << 4));
        bf16x8 vf = *(const bf16x8*)(lds + off);
        acco[nt] = __builtin_amdgcn_mfma_f32_16x16x32_bf16(pf.v, vf, acco[nt], 0, 0, 0);
      }
    }
    __syncthreads();
  }

  // deferred cross-replica l reduction (replicas cover disjoint kv)
  lrow += __shfl_xor(lrow, 16);
  lrow += __shfl_xor(lrow, 32);

  // ---- write this block's kv-partial (O unnormalized, m, l) to ws ----
#pragma unroll
  for (int nt = 0; nt < 4; ++nt)
#pragma unroll
    for (int r = 0; r < 4; ++r)
      pO[slot * 8192 + (w * 16 + g * 4 + r) * 64 + nt * 16 + col] = acco[nt][r];
  if (g == 0) {
    pml[slot * 256 + (w * 16 + col) * 2 + 0] = mrow;
    pml[slot * 256 + (w * 16 + col) * 2 + 1] = lrow;
  }
}

// ---- merge the 4 kv-partials per (head, qtile) -> att bf16 [n][256] ----
__global__ __launch_bounds__(256) void merge_kernel(
    const float* pO, const float* pml, unsigned short* att) {
  int bid = blockIdx.x;            // 256 = 128 groups x 2 row-halves
  int group = bid >> 1, half = bid & 1;
  int head = group >> 5, qtile = group & 31;
  int t = threadIdx.x;
  int qloc = half * 64 + (t >> 2);   // 0..127
  int d0 = (t & 3) * 16;
  const float* mlb = pml + group * 4 * 256 + qloc * 2;
  float mx = -1e30f;
#pragma unroll
  for (int ks = 0; ks < 4; ++ks) mx = fmaxf(mx, mlb[ks * 256]);
  float den = 0.f, num[16] = {};
#pragma unroll
  for (int ks = 0; ks < 4; ++ks) {
    float wgt = exp2f(mlb[ks * 256] - mx);
    den += wgt * mlb[ks * 256 + 1];
    const float* ob = pO + (group * 4 + ks) * 8192 + qloc * 64 + d0;
#pragma unroll
    for (int i = 0; i < 16; ++i) num[i] += wgt * ob[i];
  }
  float inv = 1.0f / den;
  union { unsigned short s[16]; bf16x8 v[2]; } ov;
#pragma unroll
  for (int i = 0; i < 16; ++i) ov.s[i] = f2b(num[i] * inv);
  unsigned short* dst = att + (qtile * 128 + qloc) * DEMB + head * HD + d0;
  *(bf16x8*)dst = ov.v[0];
  *(bf16x8*)(dst + 8) = ov.v[1];
}

// ---- output projection: att bf16 [n][256] @ wo + bo -> f32 out ----
__global__ __launch_bounds__(256) void outproj_kernel(
    const unsigned short* att, const unsigned short* wt_o, const float* bo,
    float* out) {
  int wave = threadIdx.x >> 6, lane = threadIdx.x & 63;
  int col = lane & 15, g = lane >> 4;
  int mbase = blockIdx.x * 64 + wave * 16;
  int nbase = blockIdx.y * 64;
  f32x4 acc[4] = {};
#pragma unroll
  for (int ks = 0; ks < 256; ks += 32) {
    bf16x8 af = *(const bf16x8*)(att + (mbase + col) * 256 + ks + g * 8);
#pragma unroll
    for (int nt = 0; nt < 4; ++nt) {
      bf16x8 bf_ = *(const bf16x8*)(wt_o + (nbase + nt * 16 + col) * 256 + ks + g * 8);
      acc[nt] = __builtin_amdgcn_mfma_f32_16x16x32_bf16(af, bf_, acc[nt], 0, 0, 0);
    }
  }
#pragma unroll
  for (int nt = 0; nt < 4; ++nt) {
    int c = nbase + nt * 16 + col;
    float b = bo[c];
#pragma unroll
    for (int r = 0; r < 4; ++r)
      out[(mbase + g * 4 + r) * 256 + c] = acc[nt][r] + b;
  }
}

extern "C" void kernel_launch(void* const* d_in, const int* in_sizes, int n_in,
                              void* d_out, int out_size, void* d_ws, size_t ws_size,
                              hipStream_t stream) {
  const float* q  = (const float*)d_in[0];
  const float* k  = (const float*)d_in[1];
  const float* v  = (const float*)d_in[2];
  const float* wq = (const float*)d_in[3];
  const float* bq = (const float*)d_in[4];
  const float* wk = (const float*)d_in[5];
  const float* bk = (const float*)d_in[6];
  const float* wv = (const float*)d_in[7];
  const float* bv = (const float*)d_in[8];
  const float* wo = (const float*)d_in[9];
  const float* bo = (const float*)d_in[10];
  float* out = (float*)d_out;

  char* ws = (char*)d_ws;
  float2* cs         = (float2*)ws;                          // [0, 1MB)
  unsigned short* wt = (unsigned short*)(ws + (1u << 20));   // [1, 1.5MB)
  unsigned short* qp = (unsigned short*)(ws + 1536u * 1024u); // [1.5, 3.5MB)
  unsigned short* kp = qp + NHEAD * NTOK * HD;               // [3.5, 5.5MB)
  unsigned short* vt = kp + NHEAD * NTOK * HD;               // [5.5, 7.5MB)
  unsigned short* att = vt + NHEAD * NTOK * HD;              // [7.5, 9.5MB)
  float* pO  = (float*)(ws + 9728u * 1024u);                 // [9.5, 25.5MB)
  float* pml = (float*)(ws + 26112u * 1024u);                // [25.5, 26MB)

  wtrans_kernel<<<1024, 256, 0, stream>>>(wq, wk, wv, wo, wt);
  cs_kernel<<<512, 256, 0, stream>>>(cs);
  qkvproj_kernel<<<dim3(64, 4, 3), 256, 0, stream>>>(q, k, v, wt, bq, bk, bv, cs,
                                                     qp, kp, vt);
  attn_kernel<<<512, 512, 0, stream>>>(qp, kp, vt, pO, pml);
  merge_kernel<<<256, 256, 0, stream>>>(pO, pml, att);
  outproj_kernel<<<dim3(64, 4), 256, 0, stream>>>(att, wt + 3 * 65536, bo, out);
}